// Round 10
// baseline (355.997 us; speedup 1.0000x reference)
//
#include <hip/hip_runtime.h>
#include <math.h>

#define D_ 8
#define H_ 64
#define IN_ 17
#define SLOPE_ 0.2f
#define B_ 128
#define T_ 514
#define W_ 512
#define N_ (B_*W_)            // 65536
#define RES_SZ (N_*D_)        // 524288
#define LOG_OFF RES_SZ        // 524288
#define HJ_OFF (RES_SZ + B_)  // 524416

// fp32 fwd packs (R4/R5-verified):
#define P1S 84   // [W1T row (64) | W0 row (17) | b0 | pad2]
#define P2S 68   // [W2 row (64) | b2 | Wo | pad2]
#define P2_OFF (D_*H_*P1S)
// bf16 hi/lo transposed planes for bwd, PADDED row stride 72 ushorts
// (64 would be exactly 32 banks -> R8's 16-way ds_read_b128 conflicts):
#define WS_BF (D_*H_*P1S + D_*H_*P2S)   // float offset where ushort region starts
#define BSTR 72
#define PERD 23040            // ushorts per d: 4*64*72 + 2*32*72
#define O_W2H 0
#define O_W2L 4608
#define O_W1H 9216
#define O_W1L 13824
#define O_W0H 18432
#define O_W0L 20736

typedef __attribute__((ext_vector_type(8))) short short8;
typedef __attribute__((ext_vector_type(4))) float float4v;

__device__ __forceinline__ unsigned short f2bf(float x) {   // RNE to bf16
    unsigned u = __float_as_uint(x);
    unsigned r = ((u >> 16) & 1u) + 0x7fffu;
    return (unsigned short)((u + r) >> 16);
}
__device__ __forceinline__ float bf2f(unsigned short h) {
    return __uint_as_float(((unsigned)h) << 16);
}
__device__ __forceinline__ void split2(float x, short& hi, short& lo) {
    unsigned u = __float_as_uint(x);
    hi = (short)(u >> 16);
    float r = x - __uint_as_float(u & 0xffff0000u);
    lo = (short)f2bf(r);
}

__global__ void setup_kernel(const float* __restrict__ W0, const float* __restrict__ b0,
                             const float* __restrict__ W1, const float* __restrict__ W2,
                             const float* __restrict__ b2, const float* __restrict__ Wo,
                             float* __restrict__ ws, float* __restrict__ out) {
    int d = blockIdx.x;
    float* p1 = ws + d * H_ * P1S;
    float* p2 = ws + P2_OFF + d * H_ * P2S;
    unsigned short* bfd = (unsigned short*)(ws + WS_BF) + d * PERD;
    for (int idx = threadIdx.x; idx < H_ * H_; idx += blockDim.x) {
        int r = idx >> 6, c = idx & 63;
        p1[r * P1S + c] = W1[(d * H_ + c) * H_ + r];   // W1T
        p2[r * P2S + c] = W2[(d * H_ + r) * H_ + c];   // W2 row r
        int n = r, k = c;                               // transposed bf planes
        float v2 = W2[d * H_ * H_ + k * H_ + n];        // w2t[n][k] = W2[k][n]
        unsigned short h2 = f2bf(v2);
        bfd[O_W2H + n * BSTR + k] = h2;
        bfd[O_W2L + n * BSTR + k] = f2bf(v2 - bf2f(h2));
        float v1 = W1[d * H_ * H_ + k * H_ + n];
        unsigned short h1 = f2bf(v1);
        bfd[O_W1H + n * BSTR + k] = h1;
        bfd[O_W1L + n * BSTR + k] = f2bf(v1 - bf2f(h1));
    }
    for (int r = threadIdx.x; r < H_; r += blockDim.x) {
        for (int i = 0; i < IN_; ++i)
            p1[r * P1S + 64 + i] = W0[(d * H_ + r) * IN_ + i];
        p1[r * P1S + 81] = b0[d * H_ + r];
        p2[r * P2S + 64] = b2[d * H_ + r];
        p2[r * P2S + 65] = Wo[d * H_ + r];
    }
    for (int idx = threadIdx.x; idx < 32 * H_; idx += blockDim.x) {
        int nn = idx >> 6, k = idx & 63;               // w0t[i=nn][j=k], i>=17 zero-pad
        float v = (nn < IN_) ? W0[(d * H_ + k) * IN_ + nn] : 0.0f;
        unsigned short h = f2bf(v);
        bfd[O_W0H + nn * BSTR + k] = h;
        bfd[O_W0L + nn * BSTR + k] = f2bf(v - bf2f(h));
    }
    if (d == 0 && threadIdx.x < B_) out[LOG_OFF + threadIdx.x] = 0.0f;
}

// fp32-exact forward, weights from LDS. (256,3): 170-reg budget so the
// ~20 weight VGPRs + inp[17] live in ARCH VGPRs (R9's (256,4)=128 budget
// forced VGPR_Count=64 and pushed inp/temps into AGPRs -> accvgpr_read per
// FMA -> 2x VALU issue). h1acc[64] in AGPRs is fine (1-op fmac w/ AGPR dst).
__global__ __launch_bounds__(256, 3) void fwd_kernel(
    const float* __restrict__ x, const float* __restrict__ b1g,
    const float* __restrict__ bo, const float* __restrict__ ws,
    float* __restrict__ out)
{
    __shared__ float sP1[H_ * P1S];   // 21.5 KB
    __shared__ float sP2[H_ * P2S];   // 17.4 KB
    __shared__ float sb1[H_];

    const int blk = blockIdx.x;
    const int d   = blk >> 8;
    const int t   = blk & 255;
    const int tid = threadIdx.x;
    const int n   = (t << 8) + tid;
    const int b   = n >> 9;
    const int w   = n & 511;

    {
        const float4* g1 = (const float4*)(ws + d * H_ * P1S);
        const float4* g2 = (const float4*)(ws + P2_OFF + d * H_ * P2S);
        float4* l1 = (float4*)sP1;
        float4* l2 = (float4*)sP2;
        for (int i = tid; i < H_ * P1S / 4; i += 256) l1[i] = g1[i];
        for (int i = tid; i < H_ * P2S / 4; i += 256) l2[i] = g2[i];
        if (tid < H_) sb1[tid] = b1g[d * H_ + tid];
    }

    float inp[IN_];
    {
        const float* xp = x + (b * T_ + w) * D_;
        const float4* xp4 = (const float4*)xp;
        float4 q0 = xp4[0], q1 = xp4[1], q2 = xp4[2], q3 = xp4[3];
        inp[0]=q0.x;  inp[1]=q0.y;  inp[2]=q0.z;  inp[3]=q0.w;
        inp[4]=q1.x;  inp[5]=q1.y;  inp[6]=q1.z;  inp[7]=q1.w;
        inp[8]=q2.x;  inp[9]=q2.y;  inp[10]=q2.z; inp[11]=q2.w;
        inp[12]=q3.x; inp[13]=q3.y; inp[14]=q3.z; inp[15]=q3.w;
        inp[16] = xp[16 + d];
    }
    __syncthreads();

    // ---- Phase A: layer0 dot + layer1 outer-product (W1T rows)
    float h1acc[H_];
#pragma unroll
    for (int g = 0; g < H_; ++g) h1acc[g] = sb1[g];
    unsigned long long m0 = 0ull;

#pragma unroll 1
    for (int h = 0; h < H_; ++h) {
        const float4* r4 = (const float4*)(sP1 + h * P1S);
        float4 wa = r4[16], wb = r4[17], wc = r4[18], wd = r4[19], wt = r4[20];
        float t0 = wt.y, t1 = 0.f, t2 = 0.f, t3 = 0.f;   // wt.y = b0
        t0 = fmaf(inp[0],  wa.x, t0); t1 = fmaf(inp[1],  wa.y, t1);
        t2 = fmaf(inp[2],  wa.z, t2); t3 = fmaf(inp[3],  wa.w, t3);
        t0 = fmaf(inp[4],  wb.x, t0); t1 = fmaf(inp[5],  wb.y, t1);
        t2 = fmaf(inp[6],  wb.z, t2); t3 = fmaf(inp[7],  wb.w, t3);
        t0 = fmaf(inp[8],  wc.x, t0); t1 = fmaf(inp[9],  wc.y, t1);
        t2 = fmaf(inp[10], wc.z, t2); t3 = fmaf(inp[11], wc.w, t3);
        t0 = fmaf(inp[12], wd.x, t0); t1 = fmaf(inp[13], wd.y, t1);
        t2 = fmaf(inp[14], wd.z, t2); t3 = fmaf(inp[15], wd.w, t3);
        t0 = fmaf(inp[16], wt.x, t0);
        float hv = (t0 + t2) + (t1 + t3);
        bool  p  = hv > 0.0f;
        float a0h = p ? hv : hv * SLOPE_;
        m0 |= ((unsigned long long)p) << h;
#pragma unroll
        for (int q = 0; q < 16; ++q) {
            float4 wv = r4[q];
            h1acc[4*q+0] = fmaf(a0h, wv.x, h1acc[4*q+0]);
            h1acc[4*q+1] = fmaf(a0h, wv.y, h1acc[4*q+1]);
            h1acc[4*q+2] = fmaf(a0h, wv.z, h1acc[4*q+2]);
            h1acc[4*q+3] = fmaf(a0h, wv.w, h1acc[4*q+3]);
        }
    }

    // ---- Phase B: leaky + m1
    unsigned long long m1 = 0ull;
#pragma unroll
    for (int g = 0; g < H_; ++g) {
        float hv = h1acc[g];
        bool  p  = hv > 0.0f;
        m1 |= ((unsigned long long)p) << g;
        h1acc[g] = p ? hv : hv * SLOPE_;
    }

    // ---- Phase C1: layer2 dot + out-dot + m2
    unsigned long long m2 = 0ull;
    float outv = bo[d];
#pragma unroll 1
    for (int g = 0; g < H_; ++g) {
        const float4* r4 = (const float4*)(sP2 + g * P2S);
        float4 e = r4[16];                       // e.x = b2, e.y = Wo
        float t0 = e.x, t1 = 0.f, t2 = 0.f, t3 = 0.f;
#pragma unroll
        for (int q = 0; q < 16; ++q) {
            float4 wv = r4[q];
            t0 = fmaf(h1acc[4*q+0], wv.x, t0);
            t1 = fmaf(h1acc[4*q+1], wv.y, t1);
            t2 = fmaf(h1acc[4*q+2], wv.z, t2);
            t3 = fmaf(h1acc[4*q+3], wv.w, t3);
        }
        float hv = (t0 + t2) + (t1 + t3);
        bool  p  = hv > 0.0f;
        m2 |= ((unsigned long long)p) << g;
        outv = fmaf(e.y, p ? hv : hv * SLOPE_, outv);
    }
    out[n * D_ + d] = outv;

    unsigned* outU = (unsigned*)out;
    size_t mi = (size_t)HJ_OFF + ((size_t)d * N_ + n) * 16;
    outU[mi+0] = (unsigned)(m0 & 0xffffffffull); outU[mi+1] = (unsigned)(m0 >> 32);
    outU[mi+2] = (unsigned)(m1 & 0xffffffffull); outU[mi+3] = (unsigned)(m1 >> 32);
    outU[mi+4] = (unsigned)(m2 & 0xffffffffull); outU[mi+5] = (unsigned)(m2 >> 32);
}

// split-bf16 MFMA backward (R8/R9-verified): B planes + masks in LDS, padded
// stride 72, wave-private act slots, no barriers in the GEMM chain.
__global__ __launch_bounds__(256, 2) void bwd_kernel(
    const float* __restrict__ Wo,
    const float* __restrict__ ws,
    float* __restrict__ out)
{
    __shared__ unsigned short sB[PERD];       // 46 KB
    __shared__ float sAct[4 * 16 * 68];       // 17.4 KB wave-private slots
    __shared__ unsigned sM0[256*2], sM1[256*2], sM2[256*2];
    __shared__ float sWo[H_];
    __shared__ float sRed[4];

    const int blk = blockIdx.x;
    const int d   = blk >> 8;
    const int t   = blk & 255;
    const int tid = threadIdx.x;
    const int n0  = t << 8;

    {
        const unsigned short* bfw = (const unsigned short*)(ws + WS_BF) + d * PERD;
        const uint4* src = (const uint4*)bfw;
        uint4* dst = (uint4*)sB;
        for (int i = tid; i < PERD / 8; i += 256) dst[i] = src[i];
        if (tid < H_) sWo[tid] = Wo[d * H_ + tid];
        const unsigned* outU = (const unsigned*)out;
        size_t mi = (size_t)HJ_OFF + ((size_t)d * N_ + (n0 + tid)) * 16;
        sM0[tid*2] = outU[mi+0]; sM0[tid*2+1] = outU[mi+1];
        sM1[tid*2] = outU[mi+2]; sM1[tid*2+1] = outU[mi+3];
        sM2[tid*2] = outU[mi+4]; sM2[tid*2+1] = outU[mi+5];
    }
    __syncthreads();

    const int wv   = tid >> 6;
    const int lane = tid & 63;
    const int q    = lane >> 4;
    const int c    = lane & 15;
    float* slot = sAct + wv * (16 * 68);

    short8 Bw2h[4][2], Bw2l[4][2], Bw1h[4][2], Bw1l[4][2], Bw0h[2][2], Bw0l[2][2];
#pragma unroll
    for (int nt = 0; nt < 4; ++nt)
#pragma unroll
        for (int kst = 0; kst < 2; ++kst) {
            int off = (nt*16 + c) * BSTR + (kst << 5) + (q << 3);
            Bw2h[nt][kst] = *(const short8*)(sB + O_W2H + off);
            Bw2l[nt][kst] = *(const short8*)(sB + O_W2L + off);
            Bw1h[nt][kst] = *(const short8*)(sB + O_W1H + off);
            Bw1l[nt][kst] = *(const short8*)(sB + O_W1L + off);
        }
#pragma unroll
    for (int nt = 0; nt < 2; ++nt)
#pragma unroll
        for (int kst = 0; kst < 2; ++kst) {
            int off = (nt*16 + c) * BSTR + (kst << 5) + (q << 3);
            Bw0h[nt][kst] = *(const short8*)(sB + O_W0H + off);
            Bw0l[nt][kst] = *(const short8*)(sB + O_W0L + off);
        }

    float ld = 0.0f;

#pragma unroll 1
    for (int mti = 0; mti < 4; ++mti) {
        const int sbase = wv * 64 + mti * 16;

        {
            unsigned mm = sM2[(sbase + c) * 2 + (q >> 1)];
            float* srow = slot + c * 68 + q * 16;
            const float* wop = sWo + q * 16;
#pragma unroll
            for (int ci = 0; ci < 16; ++ci) {
                int col = q * 16 + ci;
                float wv_ = wop[ci];
                srow[ci] = ((mm >> (col & 31)) & 1u) ? wv_ : wv_ * SLOPE_;
            }
        }

        short8 ah[2], al[2];
        float4v acc[4];

        // stage 1: x W2, mask m1
#pragma unroll
        for (int kst = 0; kst < 2; ++kst) {
            const float* p = slot + c * 68 + kst * 32 + q * 8;
            float4 f0 = *(const float4*)p, f1 = *(const float4*)(p + 4);
            float xs[8] = {f0.x,f0.y,f0.z,f0.w,f1.x,f1.y,f1.z,f1.w};
#pragma unroll
            for (int j = 0; j < 8; ++j) { short h8,l8; split2(xs[j],h8,l8); ah[kst][j]=h8; al[kst][j]=l8; }
        }
#pragma unroll
        for (int nt = 0; nt < 4; ++nt) {
            float4v a = {0.f,0.f,0.f,0.f};
#pragma unroll
            for (int kst = 0; kst < 2; ++kst) {
                a = __builtin_amdgcn_mfma_f32_16x16x32_bf16(ah[kst], Bw2h[nt][kst], a, 0,0,0);
                a = __builtin_amdgcn_mfma_f32_16x16x32_bf16(al[kst], Bw2h[nt][kst], a, 0,0,0);
                a = __builtin_amdgcn_mfma_f32_16x16x32_bf16(ah[kst], Bw2l[nt][kst], a, 0,0,0);
            }
            acc[nt] = a;
        }
#pragma unroll
        for (int nt = 0; nt < 4; ++nt)
#pragma unroll
            for (int r = 0; r < 4; ++r) {
                int row = q * 4 + r, col = nt * 16 + c;
                unsigned bit = (sM1[(sbase + row) * 2 + (col >> 5)] >> (col & 31)) & 1u;
                float v = acc[nt][r];
                slot[row * 68 + col] = bit ? v : v * SLOPE_;
            }

        // stage 2: x W1, mask m0
#pragma unroll
        for (int kst = 0; kst < 2; ++kst) {
            const float* p = slot + c * 68 + kst * 32 + q * 8;
            float4 f0 = *(const float4*)p, f1 = *(const float4*)(p + 4);
            float xs[8] = {f0.x,f0.y,f0.z,f0.w,f1.x,f1.y,f1.z,f1.w};
#pragma unroll
            for (int j = 0; j < 8; ++j) { short h8,l8; split2(xs[j],h8,l8); ah[kst][j]=h8; al[kst][j]=l8; }
        }
#pragma unroll
        for (int nt = 0; nt < 4; ++nt) {
            float4v a = {0.f,0.f,0.f,0.f};
#pragma unroll
            for (int kst = 0; kst < 2; ++kst) {
                a = __builtin_amdgcn_mfma_f32_16x16x32_bf16(ah[kst], Bw1h[nt][kst], a, 0,0,0);
                a = __builtin_amdgcn_mfma_f32_16x16x32_bf16(al[kst], Bw1h[nt][kst], a, 0,0,0);
                a = __builtin_amdgcn_mfma_f32_16x16x32_bf16(ah[kst], Bw1l[nt][kst], a, 0,0,0);
            }
            acc[nt] = a;
        }
#pragma unroll
        for (int nt = 0; nt < 4; ++nt)
#pragma unroll
            for (int r = 0; r < 4; ++r) {
                int row = q * 4 + r, col = nt * 16 + c;
                unsigned bit = (sM0[(sbase + row) * 2 + (col >> 5)] >> (col & 31)) & 1u;
                float v = acc[nt][r];
                slot[row * 68 + col] = bit ? v : v * SLOPE_;
            }

        // stage 3: x W0 (N=32, col16 = jac[...,16])
#pragma unroll
        for (int kst = 0; kst < 2; ++kst) {
            const float* p = slot + c * 68 + kst * 32 + q * 8;
            float4 f0 = *(const float4*)p, f1 = *(const float4*)(p + 4);
            float xs[8] = {f0.x,f0.y,f0.z,f0.w,f1.x,f1.y,f1.z,f1.w};
#pragma unroll
            for (int j = 0; j < 8; ++j) { short h8,l8; split2(xs[j],h8,l8); ah[kst][j]=h8; al[kst][j]=l8; }
        }
#pragma unroll
        for (int nt = 0; nt < 2; ++nt) {
            float4v a = {0.f,0.f,0.f,0.f};
#pragma unroll
            for (int kst = 0; kst < 2; ++kst) {
                a = __builtin_amdgcn_mfma_f32_16x16x32_bf16(ah[kst], Bw0h[nt][kst], a, 0,0,0);
                a = __builtin_amdgcn_mfma_f32_16x16x32_bf16(al[kst], Bw0h[nt][kst], a, 0,0,0);
                a = __builtin_amdgcn_mfma_f32_16x16x32_bf16(ah[kst], Bw0l[nt][kst], a, 0,0,0);
            }
            acc[nt] = a;
        }
#pragma unroll
        for (int r = 0; r < 4; ++r) {
            int gn = n0 + sbase + q * 4 + r;
            out[HJ_OFF + ((size_t)d * N_ + gn) * 16 + c] = acc[0][r];
        }
        if (c == 0) {
#pragma unroll
            for (int r = 0; r < 4; ++r) ld += logf(fabsf(acc[1][r]));
        }
    }

#pragma unroll
    for (int off = 32; off > 0; off >>= 1)
        ld += __shfl_down(ld, off, 64);
    if (lane == 0) sRed[wv] = ld;
    __syncthreads();
    if (tid == 0)
        atomicAdd(out + LOG_OFF + (t >> 1), (sRed[0] + sRed[1]) + (sRed[2] + sRed[3]));
}

extern "C" void kernel_launch(void* const* d_in, const int* in_sizes, int n_in,
                              void* d_out, int out_size, void* d_ws, size_t ws_size,
                              hipStream_t stream) {
    const float* x  = (const float*)d_in[0];
    const float* W0 = (const float*)d_in[1];
    const float* b0 = (const float*)d_in[2];
    const float* W1 = (const float*)d_in[3];
    const float* b1 = (const float*)d_in[4];
    const float* W2 = (const float*)d_in[5];
    const float* b2 = (const float*)d_in[6];
    const float* Wo = (const float*)d_in[7];
    const float* bo = (const float*)d_in[8];
    float* out = (float*)d_out;
    float* ws  = (float*)d_ws;   // ~311KB fp32 packs + ~369KB bf16 planes

    hipLaunchKernelGGL(setup_kernel, dim3(D_), dim3(256), 0, stream,
                       W0, b0, W1, W2, b2, Wo, ws, out);
    hipLaunchKernelGGL(fwd_kernel, dim3(D_ * 256), dim3(256), 0, stream,
                       x, b1, bo, ws, out);
    hipLaunchKernelGGL(bwd_kernel, dim3(D_ * 256), dim3(256), 0, stream,
                       Wo, ws, out);
}

// Round 11
// 321.463 us; speedup vs baseline: 1.1074x; 1.1074x over previous
//
#include <hip/hip_runtime.h>
#include <math.h>

#define D_ 8
#define H_ 64
#define IN_ 17
#define SLOPE_ 0.2f
#define B_ 128
#define T_ 514
#define W_ 512
#define N_ (B_*W_)            // 65536
#define RES_SZ (N_*D_)        // 524288
#define LOG_OFF RES_SZ        // 524288
#define HJ_OFF (RES_SZ + B_)  // 524416

// ws: [0, D*64*64) floats = W1T fp32 (forward scalar-load stream).
// Then bf16 hi/lo transposed planes for bwd, PADDED row stride 72 ushorts
// (64 = exactly 32 banks -> R8's 16-way ds_read_b128 conflicts).
#define WS_BF (D_*H_*H_)      // float offset where ushort region starts
#define BSTR 72
#define PERD 23040            // ushorts per d: 4*64*72 + 2*32*72
#define O_W2H 0
#define O_W2L 4608
#define O_W1H 9216
#define O_W1L 13824
#define O_W0H 18432
#define O_W0L 20736

typedef __attribute__((ext_vector_type(8))) short short8;
typedef __attribute__((ext_vector_type(4))) float float4v;

__device__ __forceinline__ unsigned short f2bf(float x) {   // RNE to bf16
    unsigned u = __float_as_uint(x);
    unsigned r = ((u >> 16) & 1u) + 0x7fffu;
    return (unsigned short)((u + r) >> 16);
}
__device__ __forceinline__ float bf2f(unsigned short h) {
    return __uint_as_float(((unsigned)h) << 16);
}
__device__ __forceinline__ void split2(float x, short& hi, short& lo) {
    unsigned u = __float_as_uint(x);
    hi = (short)(u >> 16);
    float r = x - __uint_as_float(u & 0xffff0000u);
    lo = (short)f2bf(r);
}

__global__ void setup_kernel(const float* __restrict__ W0, const float* __restrict__ W1,
                             const float* __restrict__ W2,
                             float* __restrict__ ws, float* __restrict__ out) {
    int d = blockIdx.x;
    float* w1t = ws + d * H_ * H_;
    unsigned short* bfd = (unsigned short*)(ws + WS_BF) + d * PERD;
    for (int idx = threadIdx.x; idx < H_ * H_; idx += blockDim.x) {
        int r = idx >> 6, c = idx & 63;
        w1t[idx] = W1[(d * H_ + c) * H_ + r];          // W1T[h_in][h_out]
        int n = r, k = c;
        float v2 = W2[d * H_ * H_ + k * H_ + n];        // w2t[n][k] = W2[k][n]
        unsigned short h2 = f2bf(v2);
        bfd[O_W2H + n * BSTR + k] = h2;
        bfd[O_W2L + n * BSTR + k] = f2bf(v2 - bf2f(h2));
        float v1 = W1[d * H_ * H_ + k * H_ + n];
        unsigned short h1 = f2bf(v1);
        bfd[O_W1H + n * BSTR + k] = h1;
        bfd[O_W1L + n * BSTR + k] = f2bf(v1 - bf2f(h1));
    }
    for (int idx = threadIdx.x; idx < 32 * H_; idx += blockDim.x) {
        int nn = idx >> 6, k = idx & 63;               // w0t[i=nn][j=k], i>=17 zero-pad
        float v = (nn < IN_) ? W0[(d * H_ + k) * IN_ + nn] : 0.0f;
        unsigned short h = f2bf(v);
        bfd[O_W0H + nn * BSTR + k] = h;
        bfd[O_W0L + nn * BSTR + k] = f2bf(v - bf2f(h));
    }
    if (d == 0 && threadIdx.x < B_) out[LOG_OFF + threadIdx.x] = 0.0f;
}

// fp32-exact forward, SCALAR weights (R7-verified: 96us VALU issue, the
// minimum measured; LDS-weight variants issue ~190us). Masks stashed to the
// hist_jac region for bwd.
__global__ void fwd_kernel(
    const float* __restrict__ x,
    const float* __restrict__ W0, const float* __restrict__ b0,
    const float* __restrict__ b1, const float* __restrict__ W2,
    const float* __restrict__ b2, const float* __restrict__ Wo,
    const float* __restrict__ bo, const float* __restrict__ W1T,
    float* __restrict__ out)
{
    const int bid = blockIdx.x;
    const int d   = bid >> 8;
    const int rem = bid & 255;
    const int b   = rem >> 1;
    const int w   = ((rem & 1) << 8) | threadIdx.x;
    const int n   = b * W_ + w;

    const float* __restrict__ W0d  = W0  + d * (H_ * IN_);
    const float* __restrict__ b0d  = b0  + d * H_;
    const float* __restrict__ b1d  = b1  + d * H_;
    const float* __restrict__ W2d  = W2  + d * (H_ * H_);
    const float* __restrict__ b2d  = b2  + d * H_;
    const float* __restrict__ Wod  = Wo  + d * H_;
    const float* __restrict__ W1Td = W1T + d * (H_ * H_);

    float inp[IN_];
    {
        const float* xp = x + (b * T_ + w) * D_;
        const float4* xp4 = (const float4*)xp;
        float4 q0 = xp4[0], q1 = xp4[1], q2 = xp4[2], q3 = xp4[3];
        inp[0]=q0.x;  inp[1]=q0.y;  inp[2]=q0.z;  inp[3]=q0.w;
        inp[4]=q1.x;  inp[5]=q1.y;  inp[6]=q1.z;  inp[7]=q1.w;
        inp[8]=q2.x;  inp[9]=q2.y;  inp[10]=q2.z; inp[11]=q2.w;
        inp[12]=q3.x; inp[13]=q3.y; inp[14]=q3.z; inp[15]=q3.w;
        inp[16] = xp[16 + d];
    }

    float h1acc[H_];
#pragma unroll
    for (int g = 0; g < H_; ++g) h1acc[g] = b1d[g];
    unsigned long long m0 = 0ull;

#pragma unroll 1
    for (int h = 0; h < H_; ++h) {
        const float* w0r = W0d + h * IN_;
        float t0 = b0d[h], t1 = 0.f, t2 = 0.f, t3 = 0.f;
#pragma unroll
        for (int i = 0; i < 16; i += 4) {
            t0 = fmaf(inp[i+0], w0r[i+0], t0);
            t1 = fmaf(inp[i+1], w0r[i+1], t1);
            t2 = fmaf(inp[i+2], w0r[i+2], t2);
            t3 = fmaf(inp[i+3], w0r[i+3], t3);
        }
        t0 = fmaf(inp[16], w0r[16], t0);
        float hv = (t0 + t2) + (t1 + t3);
        bool  p  = hv > 0.0f;
        float a0h = p ? hv : hv * SLOPE_;
        m0 |= ((unsigned long long)p) << h;
        const float* w1tr = W1Td + h * H_;
#pragma unroll
        for (int g = 0; g < H_; ++g) h1acc[g] = fmaf(a0h, w1tr[g], h1acc[g]);
    }

    unsigned long long m1 = 0ull;
#pragma unroll
    for (int g = 0; g < H_; ++g) {
        float hv = h1acc[g];
        bool  p  = hv > 0.0f;
        m1 |= ((unsigned long long)p) << g;
        h1acc[g] = p ? hv : hv * SLOPE_;
    }

    unsigned long long m2 = 0ull;
    float outv = bo[d];
#pragma unroll 1
    for (int g = 0; g < H_; ++g) {
        const float* w2r = W2d + g * H_;
        float t0 = b2d[g], t1 = 0.f, t2 = 0.f, t3 = 0.f;
#pragma unroll
        for (int k = 0; k < H_; k += 4) {
            t0 = fmaf(h1acc[k+0], w2r[k+0], t0);
            t1 = fmaf(h1acc[k+1], w2r[k+1], t1);
            t2 = fmaf(h1acc[k+2], w2r[k+2], t2);
            t3 = fmaf(h1acc[k+3], w2r[k+3], t3);
        }
        float hv = (t0 + t2) + (t1 + t3);
        bool  p  = hv > 0.0f;
        m2 |= ((unsigned long long)p) << g;
        outv = fmaf(Wod[g], p ? hv : hv * SLOPE_, outv);
    }
    out[n * D_ + d] = outv;

    unsigned* outU = (unsigned*)out;
    size_t mi = (size_t)HJ_OFF + ((size_t)d * N_ + n) * 16;
    outU[mi+0] = (unsigned)(m0 & 0xffffffffull); outU[mi+1] = (unsigned)(m0 >> 32);
    outU[mi+2] = (unsigned)(m1 & 0xffffffffull); outU[mi+3] = (unsigned)(m1 >> 32);
    outU[mi+4] = (unsigned)(m2 & 0xffffffffull); outU[mi+5] = (unsigned)(m2 >> 32);
}

// split-bf16 MFMA backward (R9/R10-verified) + direct register build of
// stage-1 A-fragments (Wo*sel(m2) is per-lane computable: no LDS round-trip).
__global__ __launch_bounds__(256, 2) void bwd_kernel(
    const float* __restrict__ Wo,
    const float* __restrict__ ws,
    float* __restrict__ out)
{
    __shared__ unsigned short sB[PERD];       // 46 KB
    __shared__ float sAct[4 * 16 * 68];       // 17.4 KB wave-private slots
    __shared__ unsigned sM0[256*2], sM1[256*2], sM2[256*2];
    __shared__ float sWo[H_];
    __shared__ float sRed[4];

    const int blk = blockIdx.x;
    const int d   = blk >> 8;
    const int t   = blk & 255;
    const int tid = threadIdx.x;
    const int n0  = t << 8;

    {
        const unsigned short* bfw = (const unsigned short*)(ws + WS_BF) + d * PERD;
        const uint4* src = (const uint4*)bfw;
        uint4* dst = (uint4*)sB;
        for (int i = tid; i < PERD / 8; i += 256) dst[i] = src[i];
        if (tid < H_) sWo[tid] = Wo[d * H_ + tid];
        const unsigned* outU = (const unsigned*)out;
        size_t mi = (size_t)HJ_OFF + ((size_t)d * N_ + (n0 + tid)) * 16;
        sM0[tid*2] = outU[mi+0]; sM0[tid*2+1] = outU[mi+1];
        sM1[tid*2] = outU[mi+2]; sM1[tid*2+1] = outU[mi+3];
        sM2[tid*2] = outU[mi+4]; sM2[tid*2+1] = outU[mi+5];
    }
    __syncthreads();

    const int wv   = tid >> 6;
    const int lane = tid & 63;
    const int q    = lane >> 4;
    const int c    = lane & 15;
    float* slot = sAct + wv * (16 * 68);

    short8 Bw2h[4][2], Bw2l[4][2], Bw1h[4][2], Bw1l[4][2], Bw0h[2][2], Bw0l[2][2];
#pragma unroll
    for (int nt = 0; nt < 4; ++nt)
#pragma unroll
        for (int kst = 0; kst < 2; ++kst) {
            int off = (nt*16 + c) * BSTR + (kst << 5) + (q << 3);
            Bw2h[nt][kst] = *(const short8*)(sB + O_W2H + off);
            Bw2l[nt][kst] = *(const short8*)(sB + O_W2L + off);
            Bw1h[nt][kst] = *(const short8*)(sB + O_W1H + off);
            Bw1l[nt][kst] = *(const short8*)(sB + O_W1L + off);
        }
#pragma unroll
    for (int nt = 0; nt < 2; ++nt)
#pragma unroll
        for (int kst = 0; kst < 2; ++kst) {
            int off = (nt*16 + c) * BSTR + (kst << 5) + (q << 3);
            Bw0h[nt][kst] = *(const short8*)(sB + O_W0H + off);
            Bw0l[nt][kst] = *(const short8*)(sB + O_W0L + off);
        }

    float ld = 0.0f;

#pragma unroll 1
    for (int mti = 0; mti < 4; ++mti) {
        const int sbase = wv * 64 + mti * 16;

        short8 ah[2], al[2];
        float4v acc[4];

        // stage-1 A-frags built directly: A1[m=c][k] = Wo[k]*sel(m2[row][k]),
        // k = kst*32 + q*8 + j  (bit index k&31 spans q*8+j; word index = kst)
#pragma unroll
        for (int kst = 0; kst < 2; ++kst) {
            unsigned mm = sM2[(sbase + c) * 2 + kst];
            const float* wop = sWo + kst * 32 + q * 8;
            float4 e0 = *(const float4*)wop, e1 = *(const float4*)(wop + 4);
            float xs[8] = {e0.x,e0.y,e0.z,e0.w,e1.x,e1.y,e1.z,e1.w};
#pragma unroll
            for (int j = 0; j < 8; ++j) {
                int kk = q * 8 + j;
                float v = xs[j] * (((mm >> kk) & 1u) ? 1.0f : SLOPE_);
                short h8, l8; split2(v, h8, l8);
                ah[kst][j] = h8; al[kst][j] = l8;
            }
        }
#pragma unroll
        for (int nt = 0; nt < 4; ++nt) {
            float4v a = {0.f,0.f,0.f,0.f};
#pragma unroll
            for (int kst = 0; kst < 2; ++kst) {
                a = __builtin_amdgcn_mfma_f32_16x16x32_bf16(ah[kst], Bw2h[nt][kst], a, 0,0,0);
                a = __builtin_amdgcn_mfma_f32_16x16x32_bf16(al[kst], Bw2h[nt][kst], a, 0,0,0);
                a = __builtin_amdgcn_mfma_f32_16x16x32_bf16(ah[kst], Bw2l[nt][kst], a, 0,0,0);
            }
            acc[nt] = a;
        }
#pragma unroll
        for (int nt = 0; nt < 4; ++nt)
#pragma unroll
            for (int r = 0; r < 4; ++r) {
                int row = q * 4 + r, col = nt * 16 + c;
                unsigned bit = (sM1[(sbase + row) * 2 + (col >> 5)] >> (col & 31)) & 1u;
                float v = acc[nt][r];
                slot[row * 68 + col] = bit ? v : v * SLOPE_;
            }

        // stage 2: x W1, mask m0
#pragma unroll
        for (int kst = 0; kst < 2; ++kst) {
            const float* p = slot + c * 68 + kst * 32 + q * 8;
            float4 f0 = *(const float4*)p, f1 = *(const float4*)(p + 4);
            float xs[8] = {f0.x,f0.y,f0.z,f0.w,f1.x,f1.y,f1.z,f1.w};
#pragma unroll
            for (int j = 0; j < 8; ++j) { short h8,l8; split2(xs[j],h8,l8); ah[kst][j]=h8; al[kst][j]=l8; }
        }
#pragma unroll
        for (int nt = 0; nt < 4; ++nt) {
            float4v a = {0.f,0.f,0.f,0.f};
#pragma unroll
            for (int kst = 0; kst < 2; ++kst) {
                a = __builtin_amdgcn_mfma_f32_16x16x32_bf16(ah[kst], Bw1h[nt][kst], a, 0,0,0);
                a = __builtin_amdgcn_mfma_f32_16x16x32_bf16(al[kst], Bw1h[nt][kst], a, 0,0,0);
                a = __builtin_amdgcn_mfma_f32_16x16x32_bf16(ah[kst], Bw1l[nt][kst], a, 0,0,0);
            }
            acc[nt] = a;
        }
#pragma unroll
        for (int nt = 0; nt < 4; ++nt)
#pragma unroll
            for (int r = 0; r < 4; ++r) {
                int row = q * 4 + r, col = nt * 16 + c;
                unsigned bit = (sM0[(sbase + row) * 2 + (col >> 5)] >> (col & 31)) & 1u;
                float v = acc[nt][r];
                slot[row * 68 + col] = bit ? v : v * SLOPE_;
            }

        // stage 3: x W0 (N=32, col16 = jac[...,16])
#pragma unroll
        for (int kst = 0; kst < 2; ++kst) {
            const float* p = slot + c * 68 + kst * 32 + q * 8;
            float4 f0 = *(const float4*)p, f1 = *(const float4*)(p + 4);
            float xs[8] = {f0.x,f0.y,f0.z,f0.w,f1.x,f1.y,f1.z,f1.w};
#pragma unroll
            for (int j = 0; j < 8; ++j) { short h8,l8; split2(xs[j],h8,l8); ah[kst][j]=h8; al[kst][j]=l8; }
        }
#pragma unroll
        for (int nt = 0; nt < 2; ++nt) {
            float4v a = {0.f,0.f,0.f,0.f};
#pragma unroll
            for (int kst = 0; kst < 2; ++kst) {
                a = __builtin_amdgcn_mfma_f32_16x16x32_bf16(ah[kst], Bw0h[nt][kst], a, 0,0,0);
                a = __builtin_amdgcn_mfma_f32_16x16x32_bf16(al[kst], Bw0h[nt][kst], a, 0,0,0);
                a = __builtin_amdgcn_mfma_f32_16x16x32_bf16(ah[kst], Bw0l[nt][kst], a, 0,0,0);
            }
            acc[nt] = a;
        }
#pragma unroll
        for (int r = 0; r < 4; ++r) {
            int gn = n0 + sbase + q * 4 + r;
            out[HJ_OFF + ((size_t)d * N_ + gn) * 16 + c] = acc[0][r];
        }
        if (c == 0) {
#pragma unroll
            for (int r = 0; r < 4; ++r) ld += logf(fabsf(acc[1][r]));
        }
    }

#pragma unroll
    for (int off = 32; off > 0; off >>= 1)
        ld += __shfl_down(ld, off, 64);
    if (lane == 0) sRed[wv] = ld;
    __syncthreads();
    if (tid == 0)
        atomicAdd(out + LOG_OFF + (t >> 1), (sRed[0] + sRed[1]) + (sRed[2] + sRed[3]));
}

extern "C" void kernel_launch(void* const* d_in, const int* in_sizes, int n_in,
                              void* d_out, int out_size, void* d_ws, size_t ws_size,
                              hipStream_t stream) {
    const float* x  = (const float*)d_in[0];
    const float* W0 = (const float*)d_in[1];
    const float* b0 = (const float*)d_in[2];
    const float* W1 = (const float*)d_in[3];
    const float* b1 = (const float*)d_in[4];
    const float* W2 = (const float*)d_in[5];
    const float* b2 = (const float*)d_in[6];
    const float* Wo = (const float*)d_in[7];
    const float* bo = (const float*)d_in[8];
    float* out = (float*)d_out;
    float* ws  = (float*)d_ws;   // 128KB W1T + 368KB bf16 planes

    hipLaunchKernelGGL(setup_kernel, dim3(D_), dim3(256), 0, stream, W0, W1, W2, ws, out);
    hipLaunchKernelGGL(fwd_kernel, dim3(D_ * 256), dim3(256), 0, stream,
                       x, W0, b0, b1, W2, b2, Wo, bo, ws, out);
    hipLaunchKernelGGL(bwd_kernel, dim3(D_ * 256), dim3(256), 0, stream,
                       Wo, ws, out);
}

// Round 12
// 314.252 us; speedup vs baseline: 1.1328x; 1.0229x over previous
//
#include <hip/hip_runtime.h>
#include <math.h>

#define D_ 8
#define H_ 64
#define IN_ 17
#define SLOPE_ 0.2f
#define B_ 128
#define T_ 514
#define W_ 512
#define N_ (B_*W_)            // 65536
#define RES_SZ (N_*D_)        // 524288
#define LOG_OFF RES_SZ        // 524288
#define HJ_OFF (RES_SZ + B_)  // 524416

// ws: [0, D*64*64) floats = W1T fp32 (forward scalar-load stream).
// Then bf16 hi/lo transposed planes for bwd, PADDED row stride 72 ushorts.
#define WS_BF (D_*H_*H_)      // float offset where ushort region starts
#define BSTR 72
#define PERD 23040            // ushorts per d: 4*64*72 + 2*32*72
#define O_W2H 0
#define O_W2L 4608
#define O_W1H 9216
#define O_W1L 13824
#define O_W0H 18432
#define O_W0L 20736

typedef __attribute__((ext_vector_type(8))) short short8;
typedef __attribute__((ext_vector_type(4))) float float4v;

__device__ __forceinline__ unsigned short f2bf(float x) {   // RNE to bf16
    unsigned u = __float_as_uint(x);
    unsigned r = ((u >> 16) & 1u) + 0x7fffu;
    return (unsigned short)((u + r) >> 16);
}
__device__ __forceinline__ float bf2f(unsigned short h) {
    return __uint_as_float(((unsigned)h) << 16);
}

__global__ void setup_kernel(const float* __restrict__ W0, const float* __restrict__ W1,
                             const float* __restrict__ W2,
                             float* __restrict__ ws, float* __restrict__ out) {
    int d = blockIdx.x;
    float* w1t = ws + d * H_ * H_;
    unsigned short* bfd = (unsigned short*)(ws + WS_BF) + d * PERD;
    for (int idx = threadIdx.x; idx < H_ * H_; idx += blockDim.x) {
        int r = idx >> 6, c = idx & 63;
        w1t[idx] = W1[(d * H_ + c) * H_ + r];          // W1T[h_in][h_out]
        int n = r, k = c;
        float v2 = W2[d * H_ * H_ + k * H_ + n];        // w2t[n][k] = W2[k][n]
        unsigned short h2 = f2bf(v2);
        bfd[O_W2H + n * BSTR + k] = h2;
        bfd[O_W2L + n * BSTR + k] = f2bf(v2 - bf2f(h2));
        float v1 = W1[d * H_ * H_ + k * H_ + n];
        unsigned short h1 = f2bf(v1);
        bfd[O_W1H + n * BSTR + k] = h1;
        bfd[O_W1L + n * BSTR + k] = f2bf(v1 - bf2f(h1));
    }
    for (int idx = threadIdx.x; idx < 32 * H_; idx += blockDim.x) {
        int nn = idx >> 6, k = idx & 63;               // w0t[i=nn][j=k], i>=17 zero-pad
        float v = (nn < IN_) ? W0[(d * H_ + k) * IN_ + nn] : 0.0f;
        unsigned short h = f2bf(v);
        bfd[O_W0H + nn * BSTR + k] = h;
        bfd[O_W0L + nn * BSTR + k] = f2bf(v - bf2f(h));
    }
    if (d == 0 && threadIdx.x < B_) out[LOG_OFF + threadIdx.x] = 0.0f;
}

// fp32-exact forward, SCALAR weights (R7-verified: minimum VALU issue).
// Masks stashed to the hist_jac region for bwd.
__global__ void fwd_kernel(
    const float* __restrict__ x,
    const float* __restrict__ W0, const float* __restrict__ b0,
    const float* __restrict__ b1, const float* __restrict__ W2,
    const float* __restrict__ b2, const float* __restrict__ Wo,
    const float* __restrict__ bo, const float* __restrict__ W1T,
    float* __restrict__ out)
{
    const int bid = blockIdx.x;
    const int d   = bid >> 8;
    const int rem = bid & 255;
    const int b   = rem >> 1;
    const int w   = ((rem & 1) << 8) | threadIdx.x;
    const int n   = b * W_ + w;

    const float* __restrict__ W0d  = W0  + d * (H_ * IN_);
    const float* __restrict__ b0d  = b0  + d * H_;
    const float* __restrict__ b1d  = b1  + d * H_;
    const float* __restrict__ W2d  = W2  + d * (H_ * H_);
    const float* __restrict__ b2d  = b2  + d * H_;
    const float* __restrict__ Wod  = Wo  + d * H_;
    const float* __restrict__ W1Td = W1T + d * (H_ * H_);

    float inp[IN_];
    {
        const float* xp = x + (b * T_ + w) * D_;
        const float4* xp4 = (const float4*)xp;
        float4 q0 = xp4[0], q1 = xp4[1], q2 = xp4[2], q3 = xp4[3];
        inp[0]=q0.x;  inp[1]=q0.y;  inp[2]=q0.z;  inp[3]=q0.w;
        inp[4]=q1.x;  inp[5]=q1.y;  inp[6]=q1.z;  inp[7]=q1.w;
        inp[8]=q2.x;  inp[9]=q2.y;  inp[10]=q2.z; inp[11]=q2.w;
        inp[12]=q3.x; inp[13]=q3.y; inp[14]=q3.z; inp[15]=q3.w;
        inp[16] = xp[16 + d];
    }

    float h1acc[H_];
#pragma unroll
    for (int g = 0; g < H_; ++g) h1acc[g] = b1d[g];
    unsigned long long m0 = 0ull;

#pragma unroll 1
    for (int h = 0; h < H_; ++h) {
        const float* w0r = W0d + h * IN_;
        float t0 = b0d[h], t1 = 0.f, t2 = 0.f, t3 = 0.f;
#pragma unroll
        for (int i = 0; i < 16; i += 4) {
            t0 = fmaf(inp[i+0], w0r[i+0], t0);
            t1 = fmaf(inp[i+1], w0r[i+1], t1);
            t2 = fmaf(inp[i+2], w0r[i+2], t2);
            t3 = fmaf(inp[i+3], w0r[i+3], t3);
        }
        t0 = fmaf(inp[16], w0r[16], t0);
        float hv = (t0 + t2) + (t1 + t3);
        bool  p  = hv > 0.0f;
        float a0h = p ? hv : hv * SLOPE_;
        m0 |= ((unsigned long long)p) << h;
        const float* w1tr = W1Td + h * H_;
#pragma unroll
        for (int g = 0; g < H_; ++g) h1acc[g] = fmaf(a0h, w1tr[g], h1acc[g]);
    }

    unsigned long long m1 = 0ull;
#pragma unroll
    for (int g = 0; g < H_; ++g) {
        float hv = h1acc[g];
        bool  p  = hv > 0.0f;
        m1 |= ((unsigned long long)p) << g;
        h1acc[g] = p ? hv : hv * SLOPE_;
    }

    unsigned long long m2 = 0ull;
    float outv = bo[d];
#pragma unroll 1
    for (int g = 0; g < H_; ++g) {
        const float* w2r = W2d + g * H_;
        float t0 = b2d[g], t1 = 0.f, t2 = 0.f, t3 = 0.f;
#pragma unroll
        for (int k = 0; k < H_; k += 4) {
            t0 = fmaf(h1acc[k+0], w2r[k+0], t0);
            t1 = fmaf(h1acc[k+1], w2r[k+1], t1);
            t2 = fmaf(h1acc[k+2], w2r[k+2], t2);
            t3 = fmaf(h1acc[k+3], w2r[k+3], t3);
        }
        float hv = (t0 + t2) + (t1 + t3);
        bool  p  = hv > 0.0f;
        m2 |= ((unsigned long long)p) << g;
        outv = fmaf(Wod[g], p ? hv : hv * SLOPE_, outv);
    }
    out[n * D_ + d] = outv;

    unsigned* outU = (unsigned*)out;
    size_t mi = (size_t)HJ_OFF + ((size_t)d * N_ + n) * 16;
    outU[mi+0] = (unsigned)(m0 & 0xffffffffull); outU[mi+1] = (unsigned)(m0 >> 32);
    outU[mi+2] = (unsigned)(m1 & 0xffffffffull); outU[mi+3] = (unsigned)(m1 >> 32);
    outU[mi+4] = (unsigned)(m2 & 0xffffffffull); outU[mi+5] = (unsigned)(m2 >> 32);
}

// MFMA backward, 2-product: A rounded once to bf16 (RNE, ~2^-9), B exact via
// hi+lo planes. Deletes all split2 (R11's dominant VALU cost) and cuts MFMA
// 60->40 per mti. Error ~0.3-0.5% << 2%-of-max thresholds.
__global__ __launch_bounds__(256, 2) void bwd_kernel(
    const float* __restrict__ Wo,
    const float* __restrict__ ws,
    float* __restrict__ out)
{
    __shared__ unsigned short sB[PERD];       // 46 KB
    __shared__ float sAct[4 * 16 * 68];       // 17.4 KB wave-private slots
    __shared__ unsigned sM0[256*2], sM1[256*2], sM2[256*2];
    __shared__ float sWo[H_];
    __shared__ float sRed[4];

    const int blk = blockIdx.x;
    const int d   = blk >> 8;
    const int t   = blk & 255;
    const int tid = threadIdx.x;
    const int n0  = t << 8;

    {
        const unsigned short* bfw = (const unsigned short*)(ws + WS_BF) + d * PERD;
        const uint4* src = (const uint4*)bfw;
        uint4* dst = (uint4*)sB;
        for (int i = tid; i < PERD / 8; i += 256) dst[i] = src[i];
        if (tid < H_) sWo[tid] = Wo[d * H_ + tid];
        const unsigned* outU = (const unsigned*)out;
        size_t mi = (size_t)HJ_OFF + ((size_t)d * N_ + (n0 + tid)) * 16;
        sM0[tid*2] = outU[mi+0]; sM0[tid*2+1] = outU[mi+1];
        sM1[tid*2] = outU[mi+2]; sM1[tid*2+1] = outU[mi+3];
        sM2[tid*2] = outU[mi+4]; sM2[tid*2+1] = outU[mi+5];
    }
    __syncthreads();

    const int wv   = tid >> 6;
    const int lane = tid & 63;
    const int q    = lane >> 4;
    const int c    = lane & 15;
    float* slot = sAct + wv * (16 * 68);

    short8 Bw2h[4][2], Bw2l[4][2], Bw1h[4][2], Bw1l[4][2], Bw0h[2][2], Bw0l[2][2];
#pragma unroll
    for (int nt = 0; nt < 4; ++nt)
#pragma unroll
        for (int kst = 0; kst < 2; ++kst) {
            int off = (nt*16 + c) * BSTR + (kst << 5) + (q << 3);
            Bw2h[nt][kst] = *(const short8*)(sB + O_W2H + off);
            Bw2l[nt][kst] = *(const short8*)(sB + O_W2L + off);
            Bw1h[nt][kst] = *(const short8*)(sB + O_W1H + off);
            Bw1l[nt][kst] = *(const short8*)(sB + O_W1L + off);
        }
#pragma unroll
    for (int nt = 0; nt < 2; ++nt)
#pragma unroll
        for (int kst = 0; kst < 2; ++kst) {
            int off = (nt*16 + c) * BSTR + (kst << 5) + (q << 3);
            Bw0h[nt][kst] = *(const short8*)(sB + O_W0H + off);
            Bw0l[nt][kst] = *(const short8*)(sB + O_W0L + off);
        }

    float ld = 0.0f;

#pragma unroll 1
    for (int mti = 0; mti < 4; ++mti) {
        const int sbase = wv * 64 + mti * 16;

        short8 ah[2];
        float4v acc[4];

        // stage-1 A-frags in regs: A1[m=c][k] = Wo[k]*sel(m2[row][k]), bf16 RNE
#pragma unroll
        for (int kst = 0; kst < 2; ++kst) {
            unsigned mm = sM2[(sbase + c) * 2 + kst];
            const float* wop = sWo + kst * 32 + q * 8;
            float4 e0 = *(const float4*)wop, e1 = *(const float4*)(wop + 4);
            float xs[8] = {e0.x,e0.y,e0.z,e0.w,e1.x,e1.y,e1.z,e1.w};
#pragma unroll
            for (int j = 0; j < 8; ++j) {
                int kk = q * 8 + j;
                float v = xs[j] * (((mm >> kk) & 1u) ? 1.0f : SLOPE_);
                ah[kst][j] = (short)f2bf(v);
            }
        }
#pragma unroll
        for (int nt = 0; nt < 4; ++nt) {
            float4v a = {0.f,0.f,0.f,0.f};
#pragma unroll
            for (int kst = 0; kst < 2; ++kst) {
                a = __builtin_amdgcn_mfma_f32_16x16x32_bf16(ah[kst], Bw2h[nt][kst], a, 0,0,0);
                a = __builtin_amdgcn_mfma_f32_16x16x32_bf16(ah[kst], Bw2l[nt][kst], a, 0,0,0);
            }
            acc[nt] = a;
        }
#pragma unroll
        for (int nt = 0; nt < 4; ++nt)
#pragma unroll
            for (int r = 0; r < 4; ++r) {
                int row = q * 4 + r, col = nt * 16 + c;
                unsigned bit = (sM1[(sbase + row) * 2 + (col >> 5)] >> (col & 31)) & 1u;
                float v = acc[nt][r];
                slot[row * 68 + col] = bit ? v : v * SLOPE_;
            }

        // stage 2: x W1, mask m0
#pragma unroll
        for (int kst = 0; kst < 2; ++kst) {
            const float* p = slot + c * 68 + kst * 32 + q * 8;
            float4 f0 = *(const float4*)p, f1 = *(const float4*)(p + 4);
            float xs[8] = {f0.x,f0.y,f0.z,f0.w,f1.x,f1.y,f1.z,f1.w};
#pragma unroll
            for (int j = 0; j < 8; ++j) ah[kst][j] = (short)f2bf(xs[j]);
        }
#pragma unroll
        for (int nt = 0; nt < 4; ++nt) {
            float4v a = {0.f,0.f,0.f,0.f};
#pragma unroll
            for (int kst = 0; kst < 2; ++kst) {
                a = __builtin_amdgcn_mfma_f32_16x16x32_bf16(ah[kst], Bw1h[nt][kst], a, 0,0,0);
                a = __builtin_amdgcn_mfma_f32_16x16x32_bf16(ah[kst], Bw1l[nt][kst], a, 0,0,0);
            }
            acc[nt] = a;
        }
#pragma unroll
        for (int nt = 0; nt < 4; ++nt)
#pragma unroll
            for (int r = 0; r < 4; ++r) {
                int row = q * 4 + r, col = nt * 16 + c;
                unsigned bit = (sM0[(sbase + row) * 2 + (col >> 5)] >> (col & 31)) & 1u;
                float v = acc[nt][r];
                slot[row * 68 + col] = bit ? v : v * SLOPE_;
            }

        // stage 3: x W0 (N=32, col16 = jac[...,16])
#pragma unroll
        for (int kst = 0; kst < 2; ++kst) {
            const float* p = slot + c * 68 + kst * 32 + q * 8;
            float4 f0 = *(const float4*)p, f1 = *(const float4*)(p + 4);
            float xs[8] = {f0.x,f0.y,f0.z,f0.w,f1.x,f1.y,f1.z,f1.w};
#pragma unroll
            for (int j = 0; j < 8; ++j) ah[kst][j] = (short)f2bf(xs[j]);
        }
#pragma unroll
        for (int nt = 0; nt < 2; ++nt) {
            float4v a = {0.f,0.f,0.f,0.f};
#pragma unroll
            for (int kst = 0; kst < 2; ++kst) {
                a = __builtin_amdgcn_mfma_f32_16x16x32_bf16(ah[kst], Bw0h[nt][kst], a, 0,0,0);
                a = __builtin_amdgcn_mfma_f32_16x16x32_bf16(ah[kst], Bw0l[nt][kst], a, 0,0,0);
            }
            acc[nt] = a;
        }
#pragma unroll
        for (int r = 0; r < 4; ++r) {
            int gn = n0 + sbase + q * 4 + r;
            out[HJ_OFF + ((size_t)d * N_ + gn) * 16 + c] = acc[0][r];
        }
        if (c == 0) {
#pragma unroll
            for (int r = 0; r < 4; ++r) ld += logf(fabsf(acc[1][r]));
        }
    }

#pragma unroll
    for (int off = 32; off > 0; off >>= 1)
        ld += __shfl_down(ld, off, 64);
    if (lane == 0) sRed[wv] = ld;
    __syncthreads();
    if (tid == 0)
        atomicAdd(out + LOG_OFF + (t >> 1), (sRed[0] + sRed[1]) + (sRed[2] + sRed[3]));
}

extern "C" void kernel_launch(void* const* d_in, const int* in_sizes, int n_in,
                              void* d_out, int out_size, void* d_ws, size_t ws_size,
                              hipStream_t stream) {
    const float* x  = (const float*)d_in[0];
    const float* W0 = (const float*)d_in[1];
    const float* b0 = (const float*)d_in[2];
    const float* W1 = (const float*)d_in[3];
    const float* b1 = (const float*)d_in[4];
    const float* W2 = (const float*)d_in[5];
    const float* b2 = (const float*)d_in[6];
    const float* Wo = (const float*)d_in[7];
    const float* bo = (const float*)d_in[8];
    float* out = (float*)d_out;
    float* ws  = (float*)d_ws;   // 128KB W1T + 368KB bf16 planes

    hipLaunchKernelGGL(setup_kernel, dim3(D_), dim3(256), 0, stream, W0, W1, W2, ws, out);
    hipLaunchKernelGGL(fwd_kernel, dim3(D_ * 256), dim3(256), 0, stream,
                       x, W0, b0, b1, W2, b2, Wo, bo, ws, out);
    hipLaunchKernelGGL(bwd_kernel, dim3(D_ * 256), dim3(256), 0, stream,
                       Wo, ws, out);
}

// Round 13
// 219.752 us; speedup vs baseline: 1.6200x; 1.4300x over previous
//
#include <hip/hip_runtime.h>
#include <math.h>

#define D_ 8
#define H_ 64
#define IN_ 17
#define SLOPE_ 0.2f
#define B_ 128
#define T_ 514
#define W_ 512
#define N_ (B_*W_)            // 65536
#define RES_SZ (N_*D_)        // 524288
#define LOG_OFF RES_SZ        // 524288
#define HJ_OFF (RES_SZ + B_)  // 524416

#define BSTR 72               // padded plane stride (64 = 32 banks -> conflicts)

// ws is all-ushort now. Region 1: bwd planes (R12-verified layout), per d:
#define PERD_B 23040          // [w2tH][w2tL][w1tH][w1tL][w0tH][w0tL]
#define OB_W2H 0
#define OB_W2L 4608
#define OB_W1H 9216
#define OB_W1L 13824
#define OB_W0H 18432
#define OB_W0L 20736
// Region 2: fwd planes at ushort offset FWD_U, per d 27648 ushorts:
//   f0[h][k]=W0[h][k] (64x72, k<32 used, k>=17 zero)  f1[g][k]=W1[g][k]  f2[g][k]=W2[g][k]
#define FWD_U (D_*PERD_B)
#define PERD_F 27648
#define OF_W0H 0
#define OF_W0L 4608
#define OF_W1H 9216
#define OF_W1L 13824
#define OF_W2H 18432
#define OF_W2L 23040

typedef __attribute__((ext_vector_type(8))) short short8;
typedef __attribute__((ext_vector_type(4))) float float4v;

__device__ __forceinline__ unsigned short f2bf(float x) {   // RNE to bf16
    unsigned u = __float_as_uint(x);
    unsigned r = ((u >> 16) & 1u) + 0x7fffu;
    return (unsigned short)((u + r) >> 16);
}
__device__ __forceinline__ float bf2f(unsigned short h) {
    return __uint_as_float(((unsigned)h) << 16);
}
__device__ __forceinline__ void split2(float x, short& hi, short& lo) {
    unsigned u = __float_as_uint(x);
    hi = (short)(u >> 16);
    float r = x - __uint_as_float(u & 0xffff0000u);
    lo = (short)f2bf(r);
}

__global__ void setup_kernel(const float* __restrict__ W0, const float* __restrict__ W1,
                             const float* __restrict__ W2,
                             unsigned short* __restrict__ ws, float* __restrict__ out) {
    int d = blockIdx.x;
    unsigned short* bb = ws + d * PERD_B;
    unsigned short* bf = ws + FWD_U + d * PERD_F;
    for (int idx = threadIdx.x; idx < H_ * H_; idx += blockDim.x) {
        int r = idx >> 6, c = idx & 63;
        // bwd planes: w2t[n=r][k=c] = W2[k][n]
        float v2 = W2[d * H_ * H_ + c * H_ + r];
        unsigned short h2 = f2bf(v2);
        bb[OB_W2H + r * BSTR + c] = h2;
        bb[OB_W2L + r * BSTR + c] = f2bf(v2 - bf2f(h2));
        float v1 = W1[d * H_ * H_ + c * H_ + r];
        unsigned short h1 = f2bf(v1);
        bb[OB_W1H + r * BSTR + c] = h1;
        bb[OB_W1L + r * BSTR + c] = f2bf(v1 - bf2f(h1));
        // fwd planes: f1[g=r][k=c] = W1[r][c], f2 likewise
        float f1v = W1[(d * H_ + r) * H_ + c];
        unsigned short f1h = f2bf(f1v);
        bf[OF_W1H + r * BSTR + c] = f1h;
        bf[OF_W1L + r * BSTR + c] = f2bf(f1v - bf2f(f1h));
        float f2v = W2[(d * H_ + r) * H_ + c];
        unsigned short f2h = f2bf(f2v);
        bf[OF_W2H + r * BSTR + c] = f2h;
        bf[OF_W2L + r * BSTR + c] = f2bf(f2v - bf2f(f2h));
    }
    for (int idx = threadIdx.x; idx < 32 * H_; idx += blockDim.x) {
        int nn = idx >> 6, k = idx & 63;               // bwd w0t[i=nn][j=k]
        float v = (nn < IN_) ? W0[(d * H_ + k) * IN_ + nn] : 0.0f;
        unsigned short h = f2bf(v);
        bb[OB_W0H + nn * BSTR + k] = h;
        bb[OB_W0L + nn * BSTR + k] = f2bf(v - bf2f(h));
        // fwd f0[h=k][kk=nn] = W0[k][nn] (nn>=17 zero)
        float fv = (nn < IN_) ? W0[(d * H_ + k) * IN_ + nn] : 0.0f;
        unsigned short fh = f2bf(fv);
        bf[OF_W0H + k * BSTR + nn] = fh;
        bf[OF_W0L + k * BSTR + nn] = f2bf(fv - bf2f(fh));
    }
    if (d == 0 && threadIdx.x < B_) out[LOG_OFF + threadIdx.x] = 0.0f;
}

// MFMA forward (3-product split-bf16: |h_err|~1e-4; mask flips only where
// |h|<1e-4, individually benign for all outputs). Mirrors the bwd template:
// wave-private slots, padded planes, no barriers in the chain. Masks via
// __ballot -> LDS -> coalesced global stash; residual via partial dot + shfl.
__global__ __launch_bounds__(256, 2) void fwdm_kernel(
    const float* __restrict__ x,
    const float* __restrict__ b0, const float* __restrict__ b1,
    const float* __restrict__ b2, const float* __restrict__ Wo,
    const float* __restrict__ bo, const unsigned short* __restrict__ ws,
    float* __restrict__ out)
{
    __shared__ __align__(16) unsigned short sB[PERD_F];   // 55.3 KB
    __shared__ __align__(16) float sAct[4 * 16 * 68];     // 17.4 KB
    __shared__ unsigned sM0[256*2], sM1[256*2], sM2[256*2];
    __shared__ __align__(16) float sWo[H_];

    const int blk = blockIdx.x;
    const int d   = blk >> 8;
    const int t   = blk & 255;
    const int tid = threadIdx.x;
    const int n0  = t << 8;

    {
        const uint4* src = (const uint4*)(ws + FWD_U + d * PERD_F);
        uint4* dst = (uint4*)sB;
        for (int i = tid; i < PERD_F / 8; i += 256) dst[i] = src[i];
        if (tid < H_) sWo[tid] = Wo[d * H_ + tid];
    }

    const int wv   = tid >> 6;
    const int lane = tid & 63;
    const int q    = lane >> 4;
    const int c    = lane & 15;
    float* slot = sAct + wv * (16 * 68);

    float b0v[4], b1v[4], b2v[4];
#pragma unroll
    for (int nt = 0; nt < 4; ++nt) {
        b0v[nt] = b0[d * H_ + nt * 16 + c];
        b1v[nt] = b1[d * H_ + nt * 16 + c];
        b2v[nt] = b2[d * H_ + nt * 16 + c];
    }
    const float bod = bo[d];
    __syncthreads();

#pragma unroll 1
    for (int mti = 0; mti < 4; ++mti) {
        const int sbase = wv * 64 + mti * 16;
        const int gn    = n0 + sbase + c;        // this lane's A-row sample

        short8 ah[2], al[2];
        float4v acc[4];

        // ---- stage 0: A direct from x (K=32, kst=0 only)
        {
            const float* xp = x + (((gn >> 9) * T_) + (gn & 511)) * D_;
            float xs[8] = {0,0,0,0,0,0,0,0};
            if (q < 2) {
                float4 f0 = *(const float4*)(xp + q * 8);
                float4 f1 = *(const float4*)(xp + q * 8 + 4);
                xs[0]=f0.x; xs[1]=f0.y; xs[2]=f0.z; xs[3]=f0.w;
                xs[4]=f1.x; xs[5]=f1.y; xs[6]=f1.z; xs[7]=f1.w;
            } else if (q == 2) {
                xs[0] = xp[16 + d];
            }
#pragma unroll
            for (int j = 0; j < 8; ++j) { short h8,l8; split2(xs[j],h8,l8); ah[0][j]=h8; al[0][j]=l8; }
        }
#pragma unroll
        for (int nt = 0; nt < 4; ++nt) {
            int off = (nt*16 + c) * BSTR + (q << 3);
            short8 bh = *(const short8*)(sB + OF_W0H + off);
            short8 bl = *(const short8*)(sB + OF_W0L + off);
            float4v a = {0.f,0.f,0.f,0.f};
            a = __builtin_amdgcn_mfma_f32_16x16x32_bf16(ah[0], bh, a, 0,0,0);
            a = __builtin_amdgcn_mfma_f32_16x16x32_bf16(al[0], bh, a, 0,0,0);
            a = __builtin_amdgcn_mfma_f32_16x16x32_bf16(ah[0], bl, a, 0,0,0);
            acc[nt] = a;
        }
        // epilogue 0: bias + ballot masks -> sM0 + leaky -> slot
#pragma unroll
        for (int r = 0; r < 4; ++r) {
            float hv[4]; bool p[4];
#pragma unroll
            for (int nt = 0; nt < 4; ++nt) { hv[nt] = acc[nt][r] + b0v[nt]; p[nt] = hv[nt] > 0.0f; }
            unsigned long long B0 = __ballot(p[0]), B1 = __ballot(p[1]);
            unsigned long long B2 = __ballot(p[2]), B3 = __ballot(p[3]);
            if (c == 0) {
                int row = sbase + q * 4 + r;
                sM0[row*2]   = (unsigned)((B0 >> (q*16)) & 0xffffull) | ((unsigned)((B1 >> (q*16)) & 0xffffull) << 16);
                sM0[row*2+1] = (unsigned)((B2 >> (q*16)) & 0xffffull) | ((unsigned)((B3 >> (q*16)) & 0xffffull) << 16);
            }
#pragma unroll
            for (int nt = 0; nt < 4; ++nt)
                slot[(q*4+r)*68 + nt*16 + c] = p[nt] ? hv[nt] : hv[nt] * SLOPE_;
        }

        // ---- stage 1: A from slot, B = W1 planes (K=64)
#pragma unroll
        for (int kst = 0; kst < 2; ++kst) {
            const float* p = slot + c * 68 + kst * 32 + q * 8;
            float4 f0 = *(const float4*)p, f1 = *(const float4*)(p + 4);
            float xs[8] = {f0.x,f0.y,f0.z,f0.w,f1.x,f1.y,f1.z,f1.w};
#pragma unroll
            for (int j = 0; j < 8; ++j) { short h8,l8; split2(xs[j],h8,l8); ah[kst][j]=h8; al[kst][j]=l8; }
        }
#pragma unroll
        for (int nt = 0; nt < 4; ++nt) {
            float4v a = {0.f,0.f,0.f,0.f};
#pragma unroll
            for (int kst = 0; kst < 2; ++kst) {
                int off = (nt*16 + c) * BSTR + (kst << 5) + (q << 3);
                short8 bh = *(const short8*)(sB + OF_W1H + off);
                short8 bl = *(const short8*)(sB + OF_W1L + off);
                a = __builtin_amdgcn_mfma_f32_16x16x32_bf16(ah[kst], bh, a, 0,0,0);
                a = __builtin_amdgcn_mfma_f32_16x16x32_bf16(al[kst], bh, a, 0,0,0);
                a = __builtin_amdgcn_mfma_f32_16x16x32_bf16(ah[kst], bl, a, 0,0,0);
            }
            acc[nt] = a;
        }
#pragma unroll
        for (int r = 0; r < 4; ++r) {
            float hv[4]; bool p[4];
#pragma unroll
            for (int nt = 0; nt < 4; ++nt) { hv[nt] = acc[nt][r] + b1v[nt]; p[nt] = hv[nt] > 0.0f; }
            unsigned long long B0 = __ballot(p[0]), B1 = __ballot(p[1]);
            unsigned long long B2 = __ballot(p[2]), B3 = __ballot(p[3]);
            if (c == 0) {
                int row = sbase + q * 4 + r;
                sM1[row*2]   = (unsigned)((B0 >> (q*16)) & 0xffffull) | ((unsigned)((B1 >> (q*16)) & 0xffffull) << 16);
                sM1[row*2+1] = (unsigned)((B2 >> (q*16)) & 0xffffull) | ((unsigned)((B3 >> (q*16)) & 0xffffull) << 16);
            }
#pragma unroll
            for (int nt = 0; nt < 4; ++nt)
                slot[(q*4+r)*68 + nt*16 + c] = p[nt] ? hv[nt] : hv[nt] * SLOPE_;
        }

        // ---- stage 2: A from slot, B = W2 planes (K=64)
#pragma unroll
        for (int kst = 0; kst < 2; ++kst) {
            const float* p = slot + c * 68 + kst * 32 + q * 8;
            float4 f0 = *(const float4*)p, f1 = *(const float4*)(p + 4);
            float xs[8] = {f0.x,f0.y,f0.z,f0.w,f1.x,f1.y,f1.z,f1.w};
#pragma unroll
            for (int j = 0; j < 8; ++j) { short h8,l8; split2(xs[j],h8,l8); ah[kst][j]=h8; al[kst][j]=l8; }
        }
#pragma unroll
        for (int nt = 0; nt < 4; ++nt) {
            float4v a = {0.f,0.f,0.f,0.f};
#pragma unroll
            for (int kst = 0; kst < 2; ++kst) {
                int off = (nt*16 + c) * BSTR + (kst << 5) + (q << 3);
                short8 bh = *(const short8*)(sB + OF_W2H + off);
                short8 bl = *(const short8*)(sB + OF_W2L + off);
                a = __builtin_amdgcn_mfma_f32_16x16x32_bf16(ah[kst], bh, a, 0,0,0);
                a = __builtin_amdgcn_mfma_f32_16x16x32_bf16(al[kst], bh, a, 0,0,0);
                a = __builtin_amdgcn_mfma_f32_16x16x32_bf16(ah[kst], bl, a, 0,0,0);
            }
            acc[nt] = a;
        }
#pragma unroll
        for (int r = 0; r < 4; ++r) {
            float hv[4]; bool p[4];
#pragma unroll
            for (int nt = 0; nt < 4; ++nt) { hv[nt] = acc[nt][r] + b2v[nt]; p[nt] = hv[nt] > 0.0f; }
            unsigned long long B0 = __ballot(p[0]), B1 = __ballot(p[1]);
            unsigned long long B2 = __ballot(p[2]), B3 = __ballot(p[3]);
            if (c == 0) {
                int row = sbase + q * 4 + r;
                sM2[row*2]   = (unsigned)((B0 >> (q*16)) & 0xffffull) | ((unsigned)((B1 >> (q*16)) & 0xffffull) << 16);
                sM2[row*2+1] = (unsigned)((B2 >> (q*16)) & 0xffffull) | ((unsigned)((B3 >> (q*16)) & 0xffffull) << 16);
            }
#pragma unroll
            for (int nt = 0; nt < 4; ++nt)
                slot[(q*4+r)*68 + nt*16 + c] = p[nt] ? hv[nt] : hv[nt] * SLOPE_;
        }

        // ---- residual: row c, partial over this lane's 16-col segment, shfl over q
        {
            const float* srow = slot + c * 68 + q * 16;
            const float* wop  = sWo + q * 16;
            float4 s0 = *(const float4*)srow,       s1 = *(const float4*)(srow + 4);
            float4 s2 = *(const float4*)(srow + 8), s3 = *(const float4*)(srow + 12);
            float4 w0 = *(const float4*)wop,        w1 = *(const float4*)(wop + 4);
            float4 w2 = *(const float4*)(wop + 8),  w3 = *(const float4*)(wop + 12);
            float part = s0.x*w0.x + s0.y*w0.y + s0.z*w0.z + s0.w*w0.w
                       + s1.x*w1.x + s1.y*w1.y + s1.z*w1.z + s1.w*w1.w
                       + s2.x*w2.x + s2.y*w2.y + s2.z*w2.z + s2.w*w2.w
                       + s3.x*w3.x + s3.y*w3.y + s3.z*w3.z + s3.w*w3.w;
            part += __shfl_xor(part, 16, 64);
            part += __shfl_xor(part, 32, 64);
            if (q == 0) out[gn * D_ + d] = part + bod;
        }
    }

    // ---- dump masks (coalesced): 6 words per sample
    __syncthreads();
    {
        unsigned* outU = (unsigned*)out;
        size_t mi = (size_t)HJ_OFF + ((size_t)d * N_ + (n0 + tid)) * 16;
        outU[mi+0] = sM0[tid*2]; outU[mi+1] = sM0[tid*2+1];
        outU[mi+2] = sM1[tid*2]; outU[mi+3] = sM1[tid*2+1];
        outU[mi+4] = sM2[tid*2]; outU[mi+5] = sM2[tid*2+1];
    }
}

// split-bf16 MFMA backward — byte-identical to R12 (passing), offsets rebased.
__global__ __launch_bounds__(256, 2) void bwd_kernel(
    const float* __restrict__ Wo,
    const unsigned short* __restrict__ ws,
    float* __restrict__ out)
{
    __shared__ __align__(16) unsigned short sB[PERD_B];   // 46 KB
    __shared__ __align__(16) float sAct[4 * 16 * 68];
    __shared__ unsigned sM0[256*2], sM1[256*2], sM2[256*2];
    __shared__ float sWo[H_];
    __shared__ float sRed[4];

    const int blk = blockIdx.x;
    const int d   = blk >> 8;
    const int t   = blk & 255;
    const int tid = threadIdx.x;
    const int n0  = t << 8;

    {
        const uint4* src = (const uint4*)(ws + d * PERD_B);
        uint4* dst = (uint4*)sB;
        for (int i = tid; i < PERD_B / 8; i += 256) dst[i] = src[i];
        if (tid < H_) sWo[tid] = Wo[d * H_ + tid];
        const unsigned* outU = (const unsigned*)out;
        size_t mi = (size_t)HJ_OFF + ((size_t)d * N_ + (n0 + tid)) * 16;
        sM0[tid*2] = outU[mi+0]; sM0[tid*2+1] = outU[mi+1];
        sM1[tid*2] = outU[mi+2]; sM1[tid*2+1] = outU[mi+3];
        sM2[tid*2] = outU[mi+4]; sM2[tid*2+1] = outU[mi+5];
    }
    __syncthreads();

    const int wv   = tid >> 6;
    const int lane = tid & 63;
    const int q    = lane >> 4;
    const int c    = lane & 15;
    float* slot = sAct + wv * (16 * 68);

    short8 Bw2h[4][2], Bw2l[4][2], Bw1h[4][2], Bw1l[4][2], Bw0h[2][2], Bw0l[2][2];
#pragma unroll
    for (int nt = 0; nt < 4; ++nt)
#pragma unroll
        for (int kst = 0; kst < 2; ++kst) {
            int off = (nt*16 + c) * BSTR + (kst << 5) + (q << 3);
            Bw2h[nt][kst] = *(const short8*)(sB + OB_W2H + off);
            Bw2l[nt][kst] = *(const short8*)(sB + OB_W2L + off);
            Bw1h[nt][kst] = *(const short8*)(sB + OB_W1H + off);
            Bw1l[nt][kst] = *(const short8*)(sB + OB_W1L + off);
        }
#pragma unroll
    for (int nt = 0; nt < 2; ++nt)
#pragma unroll
        for (int kst = 0; kst < 2; ++kst) {
            int off = (nt*16 + c) * BSTR + (kst << 5) + (q << 3);
            Bw0h[nt][kst] = *(const short8*)(sB + OB_W0H + off);
            Bw0l[nt][kst] = *(const short8*)(sB + OB_W0L + off);
        }

    float ld = 0.0f;

#pragma unroll 1
    for (int mti = 0; mti < 4; ++mti) {
        const int sbase = wv * 64 + mti * 16;

        short8 ah[2];
        float4v acc[4];

#pragma unroll
        for (int kst = 0; kst < 2; ++kst) {
            unsigned mm = sM2[(sbase + c) * 2 + kst];
            const float* wop = sWo + kst * 32 + q * 8;
            float4 e0 = *(const float4*)wop, e1 = *(const float4*)(wop + 4);
            float xs[8] = {e0.x,e0.y,e0.z,e0.w,e1.x,e1.y,e1.z,e1.w};
#pragma unroll
            for (int j = 0; j < 8; ++j) {
                int kk = q * 8 + j;
                float v = xs[j] * (((mm >> kk) & 1u) ? 1.0f : SLOPE_);
                ah[kst][j] = (short)f2bf(v);
            }
        }
#pragma unroll
        for (int nt = 0; nt < 4; ++nt) {
            float4v a = {0.f,0.f,0.f,0.f};
#pragma unroll
            for (int kst = 0; kst < 2; ++kst) {
                a = __builtin_amdgcn_mfma_f32_16x16x32_bf16(ah[kst], Bw2h[nt][kst], a, 0,0,0);
                a = __builtin_amdgcn_mfma_f32_16x16x32_bf16(ah[kst], Bw2l[nt][kst], a, 0,0,0);
            }
            acc[nt] = a;
        }
#pragma unroll
        for (int nt = 0; nt < 4; ++nt)
#pragma unroll
            for (int r = 0; r < 4; ++r) {
                int row = q * 4 + r, col = nt * 16 + c;
                unsigned bit = (sM1[(sbase + row) * 2 + (col >> 5)] >> (col & 31)) & 1u;
                float v = acc[nt][r];
                slot[row * 68 + col] = bit ? v : v * SLOPE_;
            }

#pragma unroll
        for (int kst = 0; kst < 2; ++kst) {
            const float* p = slot + c * 68 + kst * 32 + q * 8;
            float4 f0 = *(const float4*)p, f1 = *(const float4*)(p + 4);
            float xs[8] = {f0.x,f0.y,f0.z,f0.w,f1.x,f1.y,f1.z,f1.w};
#pragma unroll
            for (int j = 0; j < 8; ++j) ah[kst][j] = (short)f2bf(xs[j]);
        }
#pragma unroll
        for (int nt = 0; nt < 4; ++nt) {
            float4v a = {0.f,0.f,0.f,0.f};
#pragma unroll
            for (int kst = 0; kst < 2; ++kst) {
                a = __builtin_amdgcn_mfma_f32_16x16x32_bf16(ah[kst], Bw1h[nt][kst], a, 0,0,0);
                a = __builtin_amdgcn_mfma_f32_16x16x32_bf16(ah[kst], Bw1l[nt][kst], a, 0,0,0);
            }
            acc[nt] = a;
        }
#pragma unroll
        for (int nt = 0; nt < 4; ++nt)
#pragma unroll
            for (int r = 0; r < 4; ++r) {
                int row = q * 4 + r, col = nt * 16 + c;
                unsigned bit = (sM0[(sbase + row) * 2 + (col >> 5)] >> (col & 31)) & 1u;
                float v = acc[nt][r];
                slot[row * 68 + col] = bit ? v : v * SLOPE_;
            }

#pragma unroll
        for (int kst = 0; kst < 2; ++kst) {
            const float* p = slot + c * 68 + kst * 32 + q * 8;
            float4 f0 = *(const float4*)p, f1 = *(const float4*)(p + 4);
            float xs[8] = {f0.x,f0.y,f0.z,f0.w,f1.x,f1.y,f1.z,f1.w};
#pragma unroll
            for (int j = 0; j < 8; ++j) ah[kst][j] = (short)f2bf(xs[j]);
        }
#pragma unroll
        for (int nt = 0; nt < 2; ++nt) {
            float4v a = {0.f,0.f,0.f,0.f};
#pragma unroll
            for (int kst = 0; kst < 2; ++kst) {
                a = __builtin_amdgcn_mfma_f32_16x16x32_bf16(ah[kst], Bw0h[nt][kst], a, 0,0,0);
                a = __builtin_amdgcn_mfma_f32_16x16x32_bf16(ah[kst], Bw0l[nt][kst], a, 0,0,0);
            }
            acc[nt] = a;
        }
#pragma unroll
        for (int r = 0; r < 4; ++r) {
            int gn = n0 + sbase + q * 4 + r;
            out[HJ_OFF + ((size_t)d * N_ + gn) * 16 + c] = acc[0][r];
        }
        if (c == 0) {
#pragma unroll
            for (int r = 0; r < 4; ++r) ld += logf(fabsf(acc[1][r]));
        }
    }

#pragma unroll
    for (int off = 32; off > 0; off >>= 1)
        ld += __shfl_down(ld, off, 64);
    if (lane == 0) sRed[wv] = ld;
    __syncthreads();
    if (tid == 0)
        atomicAdd(out + LOG_OFF + (t >> 1), (sRed[0] + sRed[1]) + (sRed[2] + sRed[3]));
}

extern "C" void kernel_launch(void* const* d_in, const int* in_sizes, int n_in,
                              void* d_out, int out_size, void* d_ws, size_t ws_size,
                              hipStream_t stream) {
    const float* x  = (const float*)d_in[0];
    const float* W0 = (const float*)d_in[1];
    const float* b0 = (const float*)d_in[2];
    const float* W1 = (const float*)d_in[3];
    const float* b1 = (const float*)d_in[4];
    const float* W2 = (const float*)d_in[5];
    const float* b2 = (const float*)d_in[6];
    const float* Wo = (const float*)d_in[7];
    const float* bo = (const float*)d_in[8];
    float* out = (float*)d_out;
    unsigned short* ws = (unsigned short*)d_ws;   // 368KB bwd + 442KB fwd planes

    hipLaunchKernelGGL(setup_kernel, dim3(D_), dim3(256), 0, stream, W0, W1, W2, ws, out);
    hipLaunchKernelGGL(fwdm_kernel, dim3(D_ * 256), dim3(256), 0, stream,
                       x, b0, b1, b2, Wo, bo, ws, out);
    hipLaunchKernelGGL(bwd_kernel, dim3(D_ * 256), dim3(256), 0, stream,
                       Wo, ws, out);
}